// Round 2
// baseline (625.044 us; speedup 1.0000x reference)
//
#include <hip/hip_runtime.h>

// BoneLengthLoss: masked MSE over 32 bone lengths, B=524288, 37 kpts, fp32.
// ~485 MB input stream -> HBM floor ~77-91us.
//
// R1-R5 history: every global_load_lds staging variant (5 schedules, 2
// occupancy points, counted-vmcnt pipeline included) lands at ~210us =
// 3.8 B/cyc/CU consumed, with VALU 7%, HBM 16%, zero conflicts. Model:
// cold-stream glds is capped by the per-CU LDS-DMA in-order completion
// queue (~64 line entries x 64B / ~900cy miss latency ~= 4.5 B/cyc/CU).
// m13's plain-load copy hits 25.6 B/cyc/CU on the same hardware.
// R6 (this): stage via REGISTERS -- coalesced global_load_dwordx4 into a
// 2-deep register pipeline (A/B RegTiles), ds_write_b128 to LDS for the
// row transpose. Compiler inserts exact counted vmcnt per load; each
// tile's loads get ~2 compute+stage phases in flight before their
// ds_write consumes them. pred+ref both in LDS -> ONE merged compute
// pass per tile, 2 barriers/tile (was 4).

#define NKPT   37
#define ROWF   111             // floats per pose row
#define TROWS  64              // rows per tile (= lane)
#define TF4    1776            // float4 per tile per array (64*111/4)
#define WF4    444             // float4 per wave slice (6*64 + 60)
#define TMB    2368            // mask bytes per tile
#define TMW    592             // mask words per tile
#define WMW    148             // mask words per wave (2*64 + 20)
#define BLOCK  256
#define WPB    4
#define GRID   512             // 2 blocks/CU * 256 CU; 8192/512 = 16 tiles exact

constexpr int J1[32] = {1,1,1,2,3,11,11,12,13,14,15,16,12,18,20,13,19,21,16,16,24,25,24,27,29,25,28,30,17,33,34,35};
constexpr int J2[32] = {2,3,4,5,6,12,13,14,14,15,16,17,18,20,22,19,21,23,24,25,26,26,27,29,31,28,30,32,33,34,35,36};

#define LGKM0() asm volatile("s_waitcnt lgkmcnt(0)" ::: "memory")
#define BAR()   __builtin_amdgcn_s_barrier()

// ws[0]=num(f32) ws[1]=den(u32) ws[2]=mask-layout flag ws[3]=done counter
__global__ void init_detect(const unsigned int* __restrict__ mw,
                            unsigned int* __restrict__ ws) {
    const int tid = threadIdx.x;
    if (tid < 4) ws[tid] = 0u;
    __syncthreads();
    unsigned int local = 0;
    for (int i = tid; i < 1024; i += BLOCK) local |= mw[i] & 0xFFFFFF00u;
    if (__any(local != 0) && (tid & 63) == 0) atomicOr(&ws[2], 1u);
}

// One tile's worth of staged data for one wave, held in registers while the
// loads are in flight. All fields statically indexed (no scratch).
struct RegTile {
    float4 p0, p1, p2, p3, p4, p5, p6;   // pred slice: 7 float4/lane
    float4 q0, q1, q2, q3, q4, q5, q6;   // ref  slice
    unsigned int m0, m1, m2;             // mask words (byte layout)
};

__device__ __forceinline__ void ld_tile(RegTile& T,
        const float4* __restrict__ pred4, const float4* __restrict__ ref4,
        const unsigned int* __restrict__ mw, int t, int wave, int lane) {
    const float4* pb = pred4 + (size_t)t * TF4 + wave * WF4 + lane;
    const float4* qb = ref4  + (size_t)t * TF4 + wave * WF4 + lane;
    const unsigned int* mb = mw + (size_t)t * TMW + wave * WMW + lane;
    T.p0 = pb[0];   T.q0 = qb[0];
    T.p1 = pb[64];  T.q1 = qb[64];
    T.p2 = pb[128]; T.q2 = qb[128];
    T.p3 = pb[192]; T.q3 = qb[192];
    T.p4 = pb[256]; T.q4 = qb[256];
    T.p5 = pb[320]; T.q5 = qb[320];
    if (lane < WF4 - 384) { T.p6 = pb[384]; T.q6 = qb[384]; }
    T.m0 = mb[0];
    T.m1 = mb[64];
    if (lane < WMW - 128) T.m2 = mb[128];
}

__device__ __forceinline__ void st_tile(const RegTile& T, float4* sp, float4* sq,
                                        unsigned int* sm, int lane) {
    sp[lane]       = T.p0;  sq[lane]       = T.q0;
    sp[64 + lane]  = T.p1;  sq[64 + lane]  = T.q1;
    sp[128 + lane] = T.p2;  sq[128 + lane] = T.q2;
    sp[192 + lane] = T.p3;  sq[192 + lane] = T.q3;
    sp[256 + lane] = T.p4;  sq[256 + lane] = T.q4;
    sp[320 + lane] = T.p5;  sq[320 + lane] = T.q5;
    if (lane < WF4 - 384) { sp[384 + lane] = T.p6; sq[384 + lane] = T.q6; }
    sm[lane]      = T.m0;
    sm[64 + lane] = T.m1;
    if (lane < WMW - 128) sm[128 + lane] = T.m2;
}

// pose-only variants for the (never-taken) int32-mask fallback
__device__ __forceinline__ void ld_pose(RegTile& T,
        const float4* __restrict__ pred4, const float4* __restrict__ ref4,
        int t, int wave, int lane) {
    const float4* pb = pred4 + (size_t)t * TF4 + wave * WF4 + lane;
    const float4* qb = ref4  + (size_t)t * TF4 + wave * WF4 + lane;
    T.p0 = pb[0];   T.q0 = qb[0];
    T.p1 = pb[64];  T.q1 = qb[64];
    T.p2 = pb[128]; T.q2 = qb[128];
    T.p3 = pb[192]; T.q3 = qb[192];
    T.p4 = pb[256]; T.q4 = qb[256];
    T.p5 = pb[320]; T.q5 = qb[320];
    if (lane < WF4 - 384) { T.p6 = pb[384]; T.q6 = qb[384]; }
}
__device__ __forceinline__ void st_pose(const RegTile& T, float4* sp, float4* sq,
                                        int lane) {
    sp[lane]       = T.p0;  sq[lane]       = T.q0;
    sp[64 + lane]  = T.p1;  sq[64 + lane]  = T.q1;
    sp[128 + lane] = T.p2;  sq[128 + lane] = T.q2;
    sp[192 + lane] = T.p3;  sq[192 + lane] = T.q3;
    sp[256 + lane] = T.p4;  sq[256 + lane] = T.q4;
    sp[320 + lane] = T.p5;  sq[320 + lane] = T.q5;
    if (lane < WF4 - 384) { sp[384 + lane] = T.p6; sq[384 + lane] = T.q6; }
}

// Merged lens+acc: pred and ref rows both live in LDS. All offsets
// compile-time; endpoint reads CSE'd by the compiler.
template <int G>
__device__ __forceinline__ void do_tile(const float* __restrict__ sp,
                                        const float* __restrict__ sq,
                                        const unsigned char* __restrict__ sm,
                                        float& num, unsigned int& den) {
#pragma unroll
    for (int k = 0; k < 8; ++k) {
        const int a = J1[G * 8 + k], b = J2[G * 8 + k];
        const int a3 = a * 3, b3 = b * 3;
        float pdx = sp[b3] - sp[a3];
        float pdy = sp[b3 + 1] - sp[a3 + 1];
        float pdz = sp[b3 + 2] - sp[a3 + 2];
        float qdx = sq[b3] - sq[a3];
        float qdy = sq[b3 + 1] - sq[a3 + 1];
        float qdz = sq[b3 + 2] - sq[a3 + 2];
        float pl = __builtin_amdgcn_sqrtf(pdx * pdx + pdy * pdy + pdz * pdz);
        float ql = __builtin_amdgcn_sqrtf(qdx * qdx + qdy * qdy + qdz * qdz);
        unsigned int v = (unsigned int)(sm[a] & sm[b]);
        float d = pl - ql;
        num += v ? d * d : 0.0f;
        den += v;
    }
}

#define COMPUTE() do { switch (wave) { \
    case 0: do_tile<0>(sp_row, sq_row, sm_row, num, den); break; \
    case 1: do_tile<1>(sp_row, sq_row, sm_row, num, den); break; \
    case 2: do_tile<2>(sp_row, sq_row, sm_row, num, den); break; \
    default: do_tile<3>(sp_row, sq_row, sm_row, num, den); break; } } while (0)

__global__ __launch_bounds__(BLOCK, 2)
void bone_main(const float* __restrict__ pred, const float* __restrict__ ref,
               const void* __restrict__ mask, int B,
               unsigned int* __restrict__ ws, float* __restrict__ out) {
    __shared__ __align__(16) float4 s_pred[TF4];            // 28416 B
    __shared__ __align__(16) float4 s_ref[TF4];             // 28416 B
    __shared__ __align__(16) unsigned int s_maskw[TMW];     //  2368 B
    __shared__ float s_rn[WPB];
    __shared__ unsigned int s_rd[WPB];

    const int tid  = threadIdx.x;
    const int wave = tid >> 6;
    const int lane = tid & 63;          // = row within the 64-row tile

    const bool mask_bytes = (ws[2] != 0);
    const int ntiles = B / TROWS;       // 8192

    const float4* __restrict__ pred4 = (const float4*)pred;
    const float4* __restrict__ ref4  = (const float4*)ref;
    const unsigned int* __restrict__ mw = (const unsigned int*)mask;
    const int* __restrict__ mi = (const int*)mask;

    float4* spw = s_pred + wave * WF4;
    float4* sqw = s_ref  + wave * WF4;
    unsigned int* smw = s_maskw + wave * WMW;

    const float* sp_row = (const float*)s_pred + lane * ROWF;
    const float* sq_row = (const float*)s_ref  + lane * ROWF;
    const unsigned char* sm_row = (const unsigned char*)s_maskw + lane * NKPT;

    float num = 0.0f;
    unsigned int den = 0u;

    const int bid = blockIdx.x;
    const int ntb = (bid < ntiles) ? (ntiles - bid + GRID - 1) / GRID : 0;

    if (mask_bytes && ntb >= 2 && (ntb & 1) == 0) {
        // ---- register-pipelined path ----
        // Invariant at loop top (tile index j): LDS = T_j, B = T_{j+1}
        // (in flight or landed), A = T_{j+2} (in flight).
        RegTile A, B2;
        ld_tile(A,  pred4, ref4, mw, bid,        wave, lane);
        ld_tile(B2, pred4, ref4, mw, bid + GRID, wave, lane);
        st_tile(A, spw, sqw, smw, lane);         // waits A's loads (startup)
        { int tn = bid + 2 * GRID;
          if (tn < ntiles) ld_tile(A, pred4, ref4, mw, tn, wave, lane); }
        LGKM0(); BAR();
        for (int j = 0; j < ntb; j += 2) {
            COMPUTE();                           // tile bid + j*GRID
            BAR();                               // all waves done reading
            st_tile(B2, spw, sqw, smw, lane);    // waits B's loads (2 phases old)
            { int tn = bid + (j + 3) * GRID;
              if (tn < ntiles) ld_tile(B2, pred4, ref4, mw, tn, wave, lane); }
            LGKM0(); BAR();                      // LDS = T_{j+1} ready
            COMPUTE();                           // tile bid + (j+1)*GRID
            if (j + 2 < ntb) {
                BAR();
                st_tile(A, spw, sqw, smw, lane);
                { int tn = bid + (j + 4) * GRID;
                  if (tn < ntiles) ld_tile(A, pred4, ref4, mw, tn, wave, lane); }
                LGKM0(); BAR();                  // LDS = T_{j+2} ready
            }
        }
    } else {
        // ---- fallback: fully drained, handles both mask layouts ----
        for (int t = bid; t < ntiles; t += GRID) {
            RegTile A;
            ld_pose(A, pred4, ref4, t, wave, lane);
            st_pose(A, spw, sqw, lane);
            if (mask_bytes) {
                for (int i = tid; i < TMW; i += BLOCK)
                    s_maskw[i] = mw[(size_t)t * TMW + i];
            } else {
                unsigned char* smb = (unsigned char*)s_maskw;
                const int* mb = mi + (size_t)t * TMB;
                for (int i = tid; i < TMB; i += BLOCK)
                    smb[i] = (unsigned char)mb[i];
            }
            __syncthreads();
            COMPUTE();
            __syncthreads();
        }
    }

    // ---- reduce: wave shuffle -> block partials -> one atomic per block ----
#pragma unroll
    for (int off = 32; off > 0; off >>= 1) {
        num += __shfl_down(num, off, 64);
        den += __shfl_down(den, off, 64);
    }
    if (lane == 0) { s_rn[wave] = num; s_rd[wave] = den; }
    __syncthreads();
    if (tid == 0) {
        float n = s_rn[0] + s_rn[1] + s_rn[2] + s_rn[3];
        unsigned int d = s_rd[0] + s_rd[1] + s_rd[2] + s_rd[3];
        atomicAdd((float*)&ws[0], n);
        atomicAdd(&ws[1], d);
        __threadfence();
        unsigned int prev = atomicAdd(&ws[3], 1u);
        if (prev == (unsigned int)(gridDim.x - 1)) {
            float fn = atomicAdd((float*)&ws[0], 0.0f);
            unsigned int fd = atomicAdd(&ws[1], 0u);
            out[0] = fn / (float)fd;
        }
    }
}

extern "C" void kernel_launch(void* const* d_in, const int* in_sizes, int n_in,
                              void* d_out, int out_size, void* d_ws, size_t ws_size,
                              hipStream_t stream) {
    const float* pred = (const float*)d_in[0];
    const float* ref  = (const float*)d_in[1];
    const void*  mask = d_in[2];
    const int n_mask  = in_sizes[2];           // 524288 * 37 elements
    const int B       = n_mask / NKPT;
    unsigned int* ws  = (unsigned int*)d_ws;

    init_detect<<<1, BLOCK, 0, stream>>>((const unsigned int*)mask, ws);
    bone_main<<<GRID, BLOCK, 0, stream>>>(pred, ref, mask, B, ws, (float*)d_out);
}

// Round 3
// 554.241 us; speedup vs baseline: 1.1277x; 1.1277x over previous
//
#include <hip/hip_runtime.h>

// BoneLengthLoss: masked MSE over 32 bone lengths, B=524288, 37 kpts, fp32.
// ~485 MB input stream -> HBM floor ~77-91us.
//
// R1-R5: every global_load_lds staging variant lands ~210us = 3.8 B/cyc/CU
// (VALU 7%, conflicts nil). Theory: cold-stream glds capped by the per-CU
// LDS-DMA in-order completion queue; plain loads (m13) do 25.6 B/cyc/CU.
// R6: register-staged variant REGRESSED to 292us -- rocprof showed
// WRITE_SIZE 458MB == pred+ref: the RegTile aggregates were demoted to
// scratch (SROA failure from by-ref aggregate + partial conditional field
// writes), so the whole stream round-tripped through scratch. VGPR=88
// proved nothing lived in registers.
// R7 (this): same pipeline, scratch-proof: NO aggregates -- individually
// named float4 locals, all unconditionally defined (tail loads clamped
// in-bounds; only the ds_writes are exec-masked). Last iteration peeled so
// the steady-state body is branch-free SSA. Raw s_barrier + lgkmcnt(0)
// only; vmcnt never drained -- compiler inserts exact counted vmcnt waits
// before each ds_write. Loads for t+1 are in flight across the whole
// compute phase of t.

#define NKPT   37
#define ROWF   111             // floats per pose row
#define TROWS  64              // rows per tile (= lane)
#define TF4    1776            // float4 per tile per array (64*111/4)
#define WF4    444             // float4 per wave slice (6*64 + 60)
#define TMB    2368            // mask bytes per tile
#define TMW    592             // mask words per tile
#define WMW    148             // mask words per wave (2*64 + 20)
#define BLOCK  256
#define WPB    4
#define GRID   512             // 2 blocks/CU * 256 CU; 8192/512 = 16 tiles exact

constexpr int J1[32] = {1,1,1,2,3,11,11,12,13,14,15,16,12,18,20,13,19,21,16,16,24,25,24,27,29,25,28,30,17,33,34,35};
constexpr int J2[32] = {2,3,4,5,6,12,13,14,14,15,16,17,18,20,22,19,21,23,24,25,26,26,27,29,31,28,30,32,33,34,35,36};

#define LGKM0() asm volatile("s_waitcnt lgkmcnt(0)" ::: "memory")
#define BAR()   __builtin_amdgcn_s_barrier()

// ws[0]=num(f32) ws[1]=den(u32) ws[2]=mask-layout flag ws[3]=done counter
__global__ void init_detect(const unsigned int* __restrict__ mw,
                            unsigned int* __restrict__ ws) {
    const int tid = threadIdx.x;
    if (tid < 4) ws[tid] = 0u;
    __syncthreads();
    unsigned int local = 0;
    for (int i = tid; i < 1024; i += BLOCK) local |= mw[i] & 0xFFFFFF00u;
    if (__any(local != 0) && (tid & 63) == 0) atomicOr(&ws[2], 1u);
}

// Merged lens+acc: pred and ref rows both live in LDS. All offsets
// compile-time; endpoint reads CSE'd by the compiler.
template <int G>
__device__ __forceinline__ void do_tile(const float* __restrict__ sp,
                                        const float* __restrict__ sq,
                                        const unsigned char* __restrict__ sm,
                                        float& num, unsigned int& den) {
#pragma unroll
    for (int k = 0; k < 8; ++k) {
        const int a = J1[G * 8 + k], b = J2[G * 8 + k];
        const int a3 = a * 3, b3 = b * 3;
        float pdx = sp[b3] - sp[a3];
        float pdy = sp[b3 + 1] - sp[a3 + 1];
        float pdz = sp[b3 + 2] - sp[a3 + 2];
        float qdx = sq[b3] - sq[a3];
        float qdy = sq[b3 + 1] - sq[a3 + 1];
        float qdz = sq[b3 + 2] - sq[a3 + 2];
        float pl = __builtin_amdgcn_sqrtf(pdx * pdx + pdy * pdy + pdz * pdz);
        float ql = __builtin_amdgcn_sqrtf(qdx * qdx + qdy * qdy + qdz * qdz);
        unsigned int v = (unsigned int)(sm[a] & sm[b]);
        float d = pl - ql;
        num += v ? d * d : 0.0f;
        den += v;
    }
}

#define COMPUTE() do { switch (wave) { \
    case 0: do_tile<0>(sp_row, sq_row, sm_row, num, den); break; \
    case 1: do_tile<1>(sp_row, sq_row, sm_row, num, den); break; \
    case 2: do_tile<2>(sp_row, sq_row, sm_row, num, den); break; \
    default: do_tile<3>(sp_row, sq_row, sm_row, num, den); break; } } while (0)

// Issue all 17 loads for tile (t) into the named locals. All variables
// unconditionally defined: tail addresses clamped in-bounds (duplicate
// reads for tail-excess lanes; their stores are masked off).
#define LD(t) do { \
    const float4* pb = pred4 + (size_t)(t) * TF4 + wave * WF4; \
    const float4* qb = ref4  + (size_t)(t) * TF4 + wave * WF4; \
    const unsigned int* mb = mw + (size_t)(t) * TMW + wave * WMW; \
    p0 = pb[lane];        q0 = qb[lane]; \
    p1 = pb[64  + lane];  q1 = qb[64  + lane]; \
    p2 = pb[128 + lane];  q2 = qb[128 + lane]; \
    p3 = pb[192 + lane];  q3 = qb[192 + lane]; \
    p4 = pb[256 + lane];  q4 = qb[256 + lane]; \
    p5 = pb[320 + lane];  q5 = qb[320 + lane]; \
    p6 = pb[384 + lane6]; q6 = qb[384 + lane6]; \
    m0 = mb[lane]; m1 = mb[64 + lane]; m2 = mb[128 + lanem]; \
} while (0)

// ds_write the named locals. Compiler inserts counted vmcnt waits here for
// exactly the loads feeding each store (issued one full phase earlier).
#define ST() do { \
    spw[lane]       = p0;  sqw[lane]       = q0; \
    spw[64  + lane] = p1;  sqw[64  + lane] = q1; \
    spw[128 + lane] = p2;  sqw[128 + lane] = q2; \
    spw[192 + lane] = p3;  sqw[192 + lane] = q3; \
    spw[256 + lane] = p4;  sqw[256 + lane] = q4; \
    spw[320 + lane] = p5;  sqw[320 + lane] = q5; \
    if (lane < 60) { spw[384 + lane] = p6; sqw[384 + lane] = q6; } \
    smw[lane] = m0; smw[64 + lane] = m1; \
    if (lane < 20) smw[128 + lane] = m2; \
} while (0)

__global__ __launch_bounds__(BLOCK, 2)
void bone_main(const float* __restrict__ pred, const float* __restrict__ ref,
               const void* __restrict__ mask, int B,
               unsigned int* __restrict__ ws, float* __restrict__ out) {
    __shared__ __align__(16) float4 s_pred[TF4];            // 28416 B
    __shared__ __align__(16) float4 s_ref[TF4];             // 28416 B
    __shared__ __align__(16) unsigned int s_maskw[TMW];     //  2368 B
    __shared__ float s_rn[WPB];
    __shared__ unsigned int s_rd[WPB];

    const int tid  = threadIdx.x;
    const int wave = tid >> 6;
    const int lane = tid & 63;                 // = row within the 64-row tile
    const int lane6 = (lane < 60) ? lane : 59; // clamped tail indices
    const int lanem = (lane < 20) ? lane : 19;

    const bool mask_bytes = (ws[2] != 0);
    const int ntiles = B / TROWS;              // 8192

    const float4* __restrict__ pred4 = (const float4*)pred;
    const float4* __restrict__ ref4  = (const float4*)ref;
    const unsigned int* __restrict__ mw = (const unsigned int*)mask;
    const int* __restrict__ mi = (const int*)mask;

    float4* spw = s_pred + wave * WF4;
    float4* sqw = s_ref  + wave * WF4;
    unsigned int* smw = s_maskw + wave * WMW;

    const float* sp_row = (const float*)s_pred + lane * ROWF;
    const float* sq_row = (const float*)s_ref  + lane * ROWF;
    const unsigned char* sm_row = (const unsigned char*)s_maskw + lane * NKPT;

    float num = 0.0f;
    unsigned int den = 0u;

    const int bid = blockIdx.x;

    if (mask_bytes && bid < ntiles) {
        // ---- register-pipelined path (named locals only; scratch-proof) ----
        float4 p0, p1, p2, p3, p4, p5, p6;
        float4 q0, q1, q2, q3, q4, q5, q6;
        unsigned int m0, m1, m2;

        int t = bid;
        LD(t);                                  // prologue: tile t0 in flight
        for (; t + GRID < ntiles; t += GRID) {
            ST();                               // waits tile t's loads (landed)
            LD(t + GRID);                       // prefetch t+1, in flight below
            LGKM0(); BAR();                     // LDS tile t visible to all
            COMPUTE();
            LGKM0(); BAR();                     // all waves done reading
        }
        ST();                                   // peeled last tile
        LGKM0(); BAR();
        COMPUTE();
        LGKM0(); BAR();
    } else {
        // ---- fallback: fully drained, handles both mask layouts ----
        for (int t = bid; t < ntiles; t += GRID) {
            for (int i = tid; i < TF4; i += BLOCK) {
                s_pred[i] = pred4[(size_t)t * TF4 + i];
                s_ref[i]  = ref4[(size_t)t * TF4 + i];
            }
            if (mask_bytes) {
                for (int i = tid; i < TMW; i += BLOCK)
                    s_maskw[i] = mw[(size_t)t * TMW + i];
            } else {
                unsigned char* smb = (unsigned char*)s_maskw;
                const int* mb = mi + (size_t)t * TMB;
                for (int i = tid; i < TMB; i += BLOCK)
                    smb[i] = (unsigned char)mb[i];
            }
            __syncthreads();
            COMPUTE();
            __syncthreads();
        }
    }

    // ---- reduce: wave shuffle -> block partials -> one atomic per block ----
#pragma unroll
    for (int off = 32; off > 0; off >>= 1) {
        num += __shfl_down(num, off, 64);
        den += __shfl_down(den, off, 64);
    }
    if (lane == 0) { s_rn[wave] = num; s_rd[wave] = den; }
    __syncthreads();
    if (tid == 0) {
        float n = s_rn[0] + s_rn[1] + s_rn[2] + s_rn[3];
        unsigned int d = s_rd[0] + s_rd[1] + s_rd[2] + s_rd[3];
        atomicAdd((float*)&ws[0], n);
        atomicAdd(&ws[1], d);
        __threadfence();
        unsigned int prev = atomicAdd(&ws[3], 1u);
        if (prev == (unsigned int)(gridDim.x - 1)) {
            float fn = atomicAdd((float*)&ws[0], 0.0f);
            unsigned int fd = atomicAdd(&ws[1], 0u);
            out[0] = fn / (float)fd;
        }
    }
}

extern "C" void kernel_launch(void* const* d_in, const int* in_sizes, int n_in,
                              void* d_out, int out_size, void* d_ws, size_t ws_size,
                              hipStream_t stream) {
    const float* pred = (const float*)d_in[0];
    const float* ref  = (const float*)d_in[1];
    const void*  mask = d_in[2];
    const int n_mask  = in_sizes[2];           // 524288 * 37 elements
    const int B       = n_mask / NKPT;
    unsigned int* ws  = (unsigned int*)d_ws;

    init_detect<<<1, BLOCK, 0, stream>>>((const unsigned int*)mask, ws);
    bone_main<<<GRID, BLOCK, 0, stream>>>(pred, ref, mask, B, ws, (float*)d_out);
}